// Round 4
// baseline (30069.107 us; speedup 1.0000x reference)
//
#include <hip/hip_runtime.h>
#include <math.h>

#define T_FRAMES 256
#define BATCH    64
#define NH       1024
#define NG       3072   // 3*NH
#define NMELS    80
#define FCD      256

#define JB   4     // h-units per block
#define KW   128   // k-slice per wave (8 waves * 128 = 1024)
#define NBLK 256   // persistent grid size == NH/JB == #CUs

// ---------------------------------------------------------------------------
// Transpose x: [b][t][i] -> xT [t][i][b]
__global__ __launch_bounds__(256) void k_transpose_x(
    const float* __restrict__ x, float* __restrict__ xT) {
  int t = blockIdx.x;
  __shared__ float tile[BATCH][NMELS + 1];
  for (int idx = threadIdx.x; idx < BATCH * NMELS; idx += 256) {
    int b = idx / NMELS, i = idx % NMELS;
    tile[b][i] = x[((size_t)b * T_FRAMES + t) * NMELS + i];
  }
  __syncthreads();
  for (int idx = threadIdx.x; idx < BATCH * NMELS; idx += 256) {
    int i = idx / BATCH, b = idx % BATCH;
    xT[((size_t)t * NMELS + i) * BATCH + b] = tile[b][i];
  }
}

// ---------------------------------------------------------------------------
// xp[ty][g][b] = sum_k A[t0+ty][k][b] * W[g][k] + bias[g]
// grid: (NG/64, Tc), block 256.
__global__ __launch_bounds__(256) void k_gemm_xp(
    const float* __restrict__ A, const float* __restrict__ W,
    const float* __restrict__ bias, float* __restrict__ xp, int K, int t0) {
  int ty = blockIdx.y;
  int t  = t0 + ty;
  int g0 = blockIdx.x * 64;
  __shared__ float As[16][64];
  __shared__ float Bs[16][64];

  int tid = threadIdx.x;
  int b0 = (tid & 15) * 4;
  int gq = tid >> 4;
  int ar = tid >> 4;
  int ac = (tid & 15) * 4;
  int bg = tid & 63;
  int bk = (tid >> 6) * 4;

  float acc[4][4] = {{0.f}};
  const float* At = A + (size_t)t * K * BATCH;

  for (int k0 = 0; k0 < K; k0 += 16) {
    *(float4*)&As[ar][ac] = *(const float4*)&At[(size_t)(k0 + ar) * BATCH + ac];
    float4 w = *(const float4*)&W[(size_t)(g0 + bg) * K + k0 + bk];
    Bs[bk + 0][bg] = w.x; Bs[bk + 1][bg] = w.y;
    Bs[bk + 2][bg] = w.z; Bs[bk + 3][bg] = w.w;
    __syncthreads();
#pragma unroll
    for (int kt = 0; kt < 16; ++kt) {
      const float4 a  = *(const float4*)&As[kt][b0];
      const float4 g4 = *(const float4*)&Bs[kt][gq * 4];
      const float av[4] = {a.x, a.y, a.z, a.w};
      const float gv[4] = {g4.x, g4.y, g4.z, g4.w};
#pragma unroll
      for (int gi = 0; gi < 4; ++gi)
#pragma unroll
        for (int bj = 0; bj < 4; ++bj)
          acc[gi][bj] = fmaf(gv[gi], av[bj], acc[gi][bj]);
    }
    __syncthreads();
  }
#pragma unroll
  for (int gi = 0; gi < 4; ++gi) {
    int g = g0 + gq * 4 + gi;
    float bv = bias[g];
    float4 o = make_float4(acc[gi][0] + bv, acc[gi][1] + bv,
                           acc[gi][2] + bv, acc[gi][3] + bv);
    *(float4*)&xp[((size_t)ty * NG + g) * BATCH + b0] = o;
  }
}

// ---------------------------------------------------------------------------
// Persistent GRU layer kernel: runs timesteps [t0, tEnd) of one layer.
// grid: NBLK=256 blocks x 512 threads (8 waves), exactly 1 block/CU.
// Block owns JB=4 h-units (12 gate rows), whose weights live in LDS.
// Wave wv covers k in [wv*KW, wv*KW+KW). Steps separated by grid barrier.
__global__ __launch_bounds__(512, 1) void k_gru_layer(
    const float* __restrict__ xp,    // [Tc][NG][BATCH] chunk, frame t0 first
    const float* __restrict__ whh,
    const float* __restrict__ bhh,
    float* __restrict__ act,         // [T][NH][BATCH]
    int t0, int tEnd,
    unsigned* __restrict__ bar_cnt) {
  const int tid  = threadIdx.x;
  const int lane = tid & 63;
  const int wv   = tid >> 6;
  const int j0   = blockIdx.x * JB;

  __shared__ float wlds[12 * NH];        // 48 KB: row r=g*4+j, [r][k]
  __shared__ float part[JB][3][BATCH];   // 3 KB reduction tile

  // ---- stage this block's weights into LDS (once per launch) ----
  for (int i = tid; i < 12 * NH / 4; i += 512) {
    const int r = i >> 8;            // 0..11  (NH/4 = 256 float4 per row)
    const int k4 = i & 255;
    const int g = r >> 2, j = r & 3;
    ((float4*)wlds)[i] =
        *(const float4*)&whh[((size_t)(g * NH + j0 + j)) * NH + (size_t)k4 * 4];
  }
  for (int i = tid; i < JB * 3 * BATCH; i += 512) ((float*)part)[i] = 0.f;
  __syncthreads();

  unsigned gen = 1;
  for (int t = t0; t < tEnd; ++t) {
    float sum[JB][3];
#pragma unroll
    for (int j = 0; j < JB; ++j)
#pragma unroll
      for (int g = 0; g < 3; ++g) sum[j][g] = 0.f;

    if (t > 0) {
      const float* __restrict__ hp = act + (size_t)(t - 1) * NH * BATCH;
      const int k0 = wv * KW;
#pragma unroll 4
      for (int kk = 0; kk < KW; kk += 4) {
        const int k = k0 + kk;
        const float h0 = hp[(size_t)(k + 0) * BATCH + lane];
        const float h1 = hp[(size_t)(k + 1) * BATCH + lane];
        const float h2 = hp[(size_t)(k + 2) * BATCH + lane];
        const float h3 = hp[(size_t)(k + 3) * BATCH + lane];
#pragma unroll
        for (int j = 0; j < JB; ++j) {
#pragma unroll
          for (int g = 0; g < 3; ++g) {
            const float4 w4 = *(const float4*)&wlds[(g * 4 + j) * NH + k];
            float s = sum[j][g];
            s = fmaf(w4.x, h0, s);
            s = fmaf(w4.y, h1, s);
            s = fmaf(w4.z, h2, s);
            s = fmaf(w4.w, h3, s);
            sum[j][g] = s;
          }
        }
      }
    }

    // cross-wave reduce via LDS float atomics (ds_add_f32)
#pragma unroll
    for (int j = 0; j < JB; ++j)
#pragma unroll
      for (int g = 0; g < 3; ++g)
        atomicAdd(&part[j][g][lane], sum[j][g]);
    __syncthreads();

    if (tid < JB * BATCH) {
      const int j = tid >> 6;
      const int b = tid & 63;
      const float sr = part[j][0][b];
      const float sz = part[j][1][b];
      const float sn = part[j][2][b];
      part[j][0][b] = 0.f; part[j][1][b] = 0.f; part[j][2][b] = 0.f;

      const int jj = j0 + j;
      float h_old = 0.f;
      if (t > 0) h_old = act[((size_t)(t - 1) * NH + jj) * BATCH + b];

      const float* xpt = xp + (size_t)(t - t0) * NG * BATCH;
      const float xr = xpt[(size_t)(0 * NH + jj) * BATCH + b];
      const float xz = xpt[(size_t)(1 * NH + jj) * BATCH + b];
      const float xn = xpt[(size_t)(2 * NH + jj) * BATCH + b];

      const float r = 1.f / (1.f + expf(-(xr + sr + bhh[jj])));
      const float z = 1.f / (1.f + expf(-(xz + sz + bhh[NH + jj])));
      const float n = tanhf(xn + r * (sn + bhh[2 * NH + jj]));
      const float hnew = (1.f - z) * n + z * h_old;
      act[((size_t)t * NH + jj) * BATCH + b] = hnew;
    }

    if (t + 1 < tEnd) {
      // grid barrier: release h(t) to IC, then acquire (invalidate) and go.
      __syncthreads();   // all waves' stores complete (waitcnt before s_barrier)
      if (tid == 0) {
        __hip_atomic_fetch_add(bar_cnt, 1u, __ATOMIC_ACQ_REL,
                               __HIP_MEMORY_SCOPE_AGENT);
        const unsigned tgt = gen * NBLK;
        while (__hip_atomic_load(bar_cnt, __ATOMIC_ACQUIRE,
                                 __HIP_MEMORY_SCOPE_AGENT) < tgt)
          __builtin_amdgcn_s_sleep(1);
      }
      ++gen;
      __syncthreads();
    }
  }
}

// ---------------------------------------------------------------------------
// Final projection + L2 normalize.
__global__ __launch_bounds__(256) void k_proj(
    const float* __restrict__ act, const float* __restrict__ wp,
    const float* __restrict__ bp, float* __restrict__ out) {
  int b = blockIdx.x;
  int f = threadIdx.x;
  __shared__ float hs[NH];
  __shared__ float red[FCD];

  const float* hlast = act + (size_t)(T_FRAMES - 1) * NH * BATCH + b;
  for (int k = f; k < NH; k += FCD) hs[k] = hlast[(size_t)k * BATCH];
  __syncthreads();

  float acc = bp[f];
  const float* wrow = wp + (size_t)f * NH;
#pragma unroll 4
  for (int k = 0; k < NH; k += 4) {
    const float4 w4 = *(const float4*)&wrow[k];
    acc = fmaf(w4.x, hs[k], acc);
    acc = fmaf(w4.y, hs[k + 1], acc);
    acc = fmaf(w4.z, hs[k + 2], acc);
    acc = fmaf(w4.w, hs[k + 3], acc);
  }
  red[f] = acc * acc;
  __syncthreads();
  for (int s = FCD / 2; s > 0; s >>= 1) {
    if (f < s) red[f] += red[f + s];
    __syncthreads();
  }
  float nrm = sqrtf(red[0]);
  out[(size_t)b * FCD + f] = acc / fmaxf(nrm, 1e-12f);
}

// ---------------------------------------------------------------------------
extern "C" void kernel_launch(void* const* d_in, const int* in_sizes, int n_in,
                              void* d_out, int out_size, void* d_ws, size_t ws_size,
                              hipStream_t stream) {
  const float* x        = (const float*)d_in[0];
  const float* wih0     = (const float*)d_in[1];
  const float* whh0     = (const float*)d_in[2];
  const float* bih0     = (const float*)d_in[3];
  const float* bhh0     = (const float*)d_in[4];
  const float* wih_rest = (const float*)d_in[5];
  const float* whh_rest = (const float*)d_in[6];
  const float* bih_rest = (const float*)d_in[7];
  const float* bhh_rest = (const float*)d_in[8];
  const float* wp       = (const float*)d_in[9];
  const float* bp       = (const float*)d_in[10];
  float* out = (float*)d_out;

  const size_t act_elems = (size_t)T_FRAMES * NH * BATCH;    // 64 MiB
  const size_t xT_elems  = (size_t)T_FRAMES * NMELS * BATCH; //  5 MiB
  const size_t fixed     = act_elems + xT_elems;

  float* act = (float*)d_ws;
  float* xT  = act + act_elems;
  float* xp  = xT + xT_elems;

  // choose chunk Tc so that fixed + xp-chunk + barrier counter fits
  size_t ws_elems = ws_size / sizeof(float);
  int Tc = 0;
  for (int c = T_FRAMES; c >= 1; c >>= 1) {
    if (fixed + (size_t)c * NG * BATCH + 16 <= ws_elems) { Tc = c; break; }
  }
  if (Tc == 0) return;

  unsigned* bar_cnt = (unsigned*)(xp + (size_t)Tc * NG * BATCH);

  k_transpose_x<<<T_FRAMES, 256, 0, stream>>>(x, xT);

  for (int layer = 0; layer < 3; ++layer) {
    const float* A;   int K;
    const float* wih; const float* whh; const float* bih; const float* bhh;
    if (layer == 0) {
      A = xT; K = NMELS;
      wih = wih0; whh = whh0; bih = bih0; bhh = bhh0;
    } else {
      A = act; K = NH;
      wih = wih_rest + (size_t)(layer - 1) * NG * NH;
      whh = whh_rest + (size_t)(layer - 1) * NG * NH;
      bih = bih_rest + (size_t)(layer - 1) * NG;
      bhh = bhh_rest + (size_t)(layer - 1) * NG;
    }
    for (int c0 = 0; c0 < T_FRAMES; c0 += Tc) {
      dim3 gg(NG / 64, Tc);
      k_gemm_xp<<<gg, 256, 0, stream>>>(A, wih, bih, xp, K, c0);
      hipMemsetAsync(bar_cnt, 0, sizeof(unsigned), stream);
      k_gru_layer<<<NBLK, 512, 0, stream>>>(xp, whh, bhh, act,
                                            c0, c0 + Tc, bar_cnt);
    }
  }

  k_proj<<<BATCH, FCD, 0, stream>>>(act, wp, bp, out);
}

// Round 5
// 18996.956 us; speedup vs baseline: 1.5828x; 1.5828x over previous
//
#include <hip/hip_runtime.h>
#include <math.h>

#define T_FRAMES 256
#define BATCH    64
#define NH       1024
#define NG       3072   // 3*NH
#define NMELS    80
#define FCD      256

// ---- persistent GRU geometry ----
#define NGRP   4                  // batch groups
#define GB     16                 // batches per group (MFMA N)
#define JBLK   16                 // j's per block (MFMA M)
#define NBLK_G 64                 // blocks per group = NH/JBLK
#define NBLK   (NGRP * NBLK_G)    // 256 blocks = 1/CU
#define WAVES  8
#define KSL    (NH / WAVES)       // 128 k per wave
#define KTW    (KSL / 32)         // 4 ktiles per wave

typedef __bf16 bf16x8 __attribute__((ext_vector_type(8)));
typedef float  f32x4  __attribute__((ext_vector_type(4)));

// ---------------------------------------------------------------------------
__global__ __launch_bounds__(256) void k_transpose_x(
    const float* __restrict__ x, float* __restrict__ xT) {
  int t = blockIdx.x;
  __shared__ float tile[BATCH][NMELS + 1];
  for (int idx = threadIdx.x; idx < BATCH * NMELS; idx += 256) {
    int b = idx / NMELS, i = idx % NMELS;
    tile[b][i] = x[((size_t)b * T_FRAMES + t) * NMELS + i];
  }
  __syncthreads();
  for (int idx = threadIdx.x; idx < BATCH * NMELS; idx += 256) {
    int i = idx / BATCH, b = idx % BATCH;
    xT[((size_t)t * NMELS + i) * BATCH + b] = tile[b][i];
  }
}

// ---------------------------------------------------------------------------
// xp[ty][g][b] = sum_k A[t0+ty][k][b] * W[g][k] + bias[g]
__global__ __launch_bounds__(256) void k_gemm_xp(
    const float* __restrict__ A, const float* __restrict__ W,
    const float* __restrict__ bias, float* __restrict__ xp, int K, int t0) {
  int ty = blockIdx.y;
  int t  = t0 + ty;
  int g0 = blockIdx.x * 64;
  __shared__ float As[16][64];
  __shared__ float Bs[16][64];

  int tid = threadIdx.x;
  int b0 = (tid & 15) * 4;
  int gq = tid >> 4;
  int ar = tid >> 4;
  int ac = (tid & 15) * 4;
  int bg = tid & 63;
  int bk = (tid >> 6) * 4;

  float acc[4][4] = {{0.f}};
  const float* At = A + (size_t)t * K * BATCH;

  for (int k0 = 0; k0 < K; k0 += 16) {
    *(float4*)&As[ar][ac] = *(const float4*)&At[(size_t)(k0 + ar) * BATCH + ac];
    float4 w = *(const float4*)&W[(size_t)(g0 + bg) * K + k0 + bk];
    Bs[bk + 0][bg] = w.x; Bs[bk + 1][bg] = w.y;
    Bs[bk + 2][bg] = w.z; Bs[bk + 3][bg] = w.w;
    __syncthreads();
#pragma unroll
    for (int kt = 0; kt < 16; ++kt) {
      const float4 a  = *(const float4*)&As[kt][b0];
      const float4 g4 = *(const float4*)&Bs[kt][gq * 4];
      const float av[4] = {a.x, a.y, a.z, a.w};
      const float gv[4] = {g4.x, g4.y, g4.z, g4.w};
#pragma unroll
      for (int gi = 0; gi < 4; ++gi)
#pragma unroll
        for (int bj = 0; bj < 4; ++bj)
          acc[gi][bj] = fmaf(gv[gi], av[bj], acc[gi][bj]);
    }
    __syncthreads();
  }
#pragma unroll
  for (int gi = 0; gi < 4; ++gi) {
    int g = g0 + gq * 4 + gi;
    float bv = bias[g];
    float4 o = make_float4(acc[gi][0] + bv, acc[gi][1] + bv,
                           acc[gi][2] + bv, acc[gi][3] + bv);
    *(float4*)&xp[((size_t)ty * NG + g) * BATCH + b0] = o;
  }
}

// ---------------------------------------------------------------------------
// Persistent MFMA GRU layer. 256 blocks x 512 threads (8 waves), 1 block/CU.
// Group (4 of them) = 64 blocks, owns 16 batches. Block owns 16 j's.
// Wave wv holds weights for 3 gates x 16 j x 128 k as bf16 hi/lo in VGPRs.
// h exchanged via hsp (bf16, B-frag layout, hi/lo, ping-pong on t parity).
__global__ __launch_bounds__(512, 2) void k_gru_layer(
    const float* __restrict__ xp,     // [Tc][NG][BATCH], frame t0 first
    const float* __restrict__ whh,    // [NG][NH]
    const float* __restrict__ bhh,    // [NG]
    float* __restrict__ act,          // [T][NH][BATCH]
    __bf16* __restrict__ hsp_hi,      // [2][NGRP][32][64][8]
    __bf16* __restrict__ hsp_lo,
    unsigned* __restrict__ bar,       // [NGRP][64]
    int t0, int tEnd) {
  const int tid = threadIdx.x;
  const int l   = tid & 63;
  const int wv  = tid >> 6;
  // XCD-friendly swizzle: group g <- blocks with blockIdx%8 in {2g, 2g+1}
  const int grp    = (blockIdx.x & 7) >> 1;
  const int blk_in = (blockIdx.x >> 3) * 2 + (blockIdx.x & 1);
  const int j0 = blk_in * JBLK;
  const int n0 = grp * GB;

  __shared__ float part[3][JBLK][GB];   // 3 KB

  // ---- stage weights into VGPRs as bf16 hi/lo fragments ----
  const int row_j = j0 + (l & 15);
  const int kbase = wv * KSL + (l >> 4) * 8;
  bf16x8 whi[3][KTW], wlo[3][KTW];
#pragma unroll
  for (int g = 0; g < 3; ++g) {
#pragma unroll
    for (int kt = 0; kt < KTW; ++kt) {
      const float* wp8 = whh + (size_t)(g * NH + row_j) * NH + kbase + kt * 32;
      float4 w0 = *(const float4*)wp8;
      float4 w1 = *(const float4*)(wp8 + 4);
      float f[8] = {w0.x, w0.y, w0.z, w0.w, w1.x, w1.y, w1.z, w1.w};
      bf16x8 hi, lo;
#pragma unroll
      for (int e = 0; e < 8; ++e) {
        __bf16 hv = (__bf16)f[e];
        hi[e] = hv;
        lo[e] = (__bf16)(f[e] - (float)hv);
      }
      whi[g][kt] = hi; wlo[g][kt] = lo;
    }
  }

  // gating-thread state (tid < 256): jl = tid>>4, b = tid&15
  const int jl = tid >> 4;
  const int b  = tid & 15;
  const int j  = j0 + (jl & 15);
  float hprev = 0.f, bhr = 0.f, bhz = 0.f, bhn = 0.f;
  if (tid < 256) {
    if (t0 > 0) hprev = act[((size_t)(t0 - 1) * NH + j) * BATCH + n0 + b];
    bhr = bhh[j]; bhz = bhh[NH + j]; bhn = bhh[2 * NH + j];
  }

  for (int i = tid; i < 3 * JBLK * GB; i += 512) ((float*)part)[i] = 0.f;
  __syncthreads();

  unsigned gen = 1;
  for (int t = t0; t < tEnd; ++t) {
    const int rpar = (t + 1) & 1;   // where h(t-1) lives
    const int wpar = t & 1;         // where h(t) goes

    // early xp loads (complete during MFMA phase)
    float xr = 0.f, xz = 0.f, xn = 0.f;
    if (tid < 256) {
      const float* xpt = xp + (size_t)(t - t0) * NG * BATCH;
      xr = xpt[(size_t)(0 * NH + j) * BATCH + n0 + b];
      xz = xpt[(size_t)(1 * NH + j) * BATCH + n0 + b];
      xn = xpt[(size_t)(2 * NH + j) * BATCH + n0 + b];
    }

    // ---- MFMA phase: partial gh over this wave's k-slice ----
    const size_t fb = ((size_t)(rpar * NGRP + grp) * 32 + wv * KTW) * 512 +
                      (size_t)l * 8;
    bf16x8 bh[KTW], bl[KTW];
#pragma unroll
    for (int kt = 0; kt < KTW; ++kt) {
      bh[kt] = *(const bf16x8*)(hsp_hi + fb + (size_t)kt * 512);
      bl[kt] = *(const bf16x8*)(hsp_lo + fb + (size_t)kt * 512);
    }
    f32x4 acc[3];
#pragma unroll
    for (int g = 0; g < 3; ++g) acc[g] = (f32x4){0.f, 0.f, 0.f, 0.f};
#pragma unroll
    for (int kt = 0; kt < KTW; ++kt) {
#pragma unroll
      for (int g = 0; g < 3; ++g) {
        acc[g] = __builtin_amdgcn_mfma_f32_16x16x32_bf16(whi[g][kt], bh[kt], acc[g], 0, 0, 0);
        acc[g] = __builtin_amdgcn_mfma_f32_16x16x32_bf16(whi[g][kt], bl[kt], acc[g], 0, 0, 0);
        acc[g] = __builtin_amdgcn_mfma_f32_16x16x32_bf16(wlo[g][kt], bh[kt], acc[g], 0, 0, 0);
      }
    }
    // cross-wave reduce: C row=(l>>4)*4+q, col=l&15
#pragma unroll
    for (int g = 0; g < 3; ++g)
#pragma unroll
      for (int q = 0; q < 4; ++q)
        atomicAdd(&part[g][(l >> 4) * 4 + q][l & 15], acc[g][q]);
    __syncthreads();

    // ---- gating ----
    if (tid < 256) {
      const float ghr = part[0][jl][b];
      const float ghz = part[1][jl][b];
      const float ghn = part[2][jl][b];
      part[0][jl][b] = 0.f; part[1][jl][b] = 0.f; part[2][jl][b] = 0.f;

      const float r = 1.f / (1.f + expf(-(xr + ghr + bhr)));
      const float z = 1.f / (1.f + expf(-(xz + ghz + bhz)));
      const float n = tanhf(xn + r * (ghn + bhn));
      const float h = (1.f - z) * n + z * hprev;
      hprev = h;
      act[((size_t)t * NH + j) * BATCH + n0 + b] = h;

      const __bf16 hh = (__bf16)h;
      const __bf16 hl = (__bf16)(h - (float)hh);
      const size_t fo = ((size_t)(wpar * NGRP + grp) * 32 + (j >> 5)) * 512 +
                        (size_t)(((j & 31) >> 3) * 16 + b) * 8 + (j & 7);
      hsp_hi[fo] = hh;
      hsp_lo[fo] = hl;
    }

    // ---- per-group barrier (release h(t), acquire others') ----
    if (t + 1 < tEnd) {
      __syncthreads();
      if (tid == 0) {
        unsigned* c = bar + grp * 64;
        __hip_atomic_fetch_add(c, 1u, __ATOMIC_ACQ_REL, __HIP_MEMORY_SCOPE_AGENT);
        const unsigned tgt = gen * NBLK_G;
        while (__hip_atomic_load(c, __ATOMIC_ACQUIRE, __HIP_MEMORY_SCOPE_AGENT) < tgt)
          __builtin_amdgcn_s_sleep(2);
      }
      ++gen;
      __syncthreads();
    }
  }
}

// ---------------------------------------------------------------------------
__global__ __launch_bounds__(256) void k_proj(
    const float* __restrict__ act, const float* __restrict__ wp,
    const float* __restrict__ bp, float* __restrict__ out) {
  int b = blockIdx.x;
  int f = threadIdx.x;
  __shared__ float hs[NH];
  __shared__ float red[FCD];

  const float* hlast = act + (size_t)(T_FRAMES - 1) * NH * BATCH + b;
  for (int k = f; k < NH; k += FCD) hs[k] = hlast[(size_t)k * BATCH];
  __syncthreads();

  float acc = bp[f];
  const float* wrow = wp + (size_t)f * NH;
#pragma unroll 4
  for (int k = 0; k < NH; k += 4) {
    const float4 w4 = *(const float4*)&wrow[k];
    acc = fmaf(w4.x, hs[k], acc);
    acc = fmaf(w4.y, hs[k + 1], acc);
    acc = fmaf(w4.z, hs[k + 2], acc);
    acc = fmaf(w4.w, hs[k + 3], acc);
  }
  red[f] = acc * acc;
  __syncthreads();
  for (int s = FCD / 2; s > 0; s >>= 1) {
    if (f < s) red[f] += red[f + s];
    __syncthreads();
  }
  float nrm = sqrtf(red[0]);
  out[(size_t)b * FCD + f] = acc / fmaxf(nrm, 1e-12f);
}

// ---------------------------------------------------------------------------
extern "C" void kernel_launch(void* const* d_in, const int* in_sizes, int n_in,
                              void* d_out, int out_size, void* d_ws, size_t ws_size,
                              hipStream_t stream) {
  const float* x        = (const float*)d_in[0];
  const float* wih0     = (const float*)d_in[1];
  const float* whh0     = (const float*)d_in[2];
  const float* bih0     = (const float*)d_in[3];
  const float* bhh0     = (const float*)d_in[4];
  const float* wih_rest = (const float*)d_in[5];
  const float* whh_rest = (const float*)d_in[6];
  const float* bih_rest = (const float*)d_in[7];
  const float* bhh_rest = (const float*)d_in[8];
  const float* wp       = (const float*)d_in[9];
  const float* bp       = (const float*)d_in[10];
  float* out = (float*)d_out;

  // ---- workspace layout (bytes) ----
  const size_t act_b = (size_t)T_FRAMES * NH * BATCH * 4;     // 67,108,864
  const size_t xT_b  = (size_t)T_FRAMES * NMELS * BATCH * 4;  //  5,242,880
  const size_t hsp_elems = (size_t)2 * NGRP * 32 * 64 * 8;    // 131,072 bf16
  const size_t hsp_b = hsp_elems * 2;                         // 262,144 each
  const size_t bar_b = 4096;
  const size_t fixed = act_b + xT_b + 2 * hsp_b + bar_b;

  char* wsb = (char*)d_ws;
  float*    act    = (float*)wsb;
  float*    xT     = (float*)(wsb + act_b);
  __bf16*   hsp_hi = (__bf16*)(wsb + act_b + xT_b);
  __bf16*   hsp_lo = hsp_hi + hsp_elems;
  unsigned* bar    = (unsigned*)(wsb + act_b + xT_b + 2 * hsp_b);
  float*    xp     = (float*)(wsb + fixed);

  int Tc = 0;
  for (int c = T_FRAMES; c >= 1; c >>= 1) {
    if (fixed + (size_t)c * NG * BATCH * 4 <= ws_size) { Tc = c; break; }
  }
  if (Tc == 0) return;

  const size_t xp_stride = (size_t)NG * BATCH;

  k_transpose_x<<<T_FRAMES, 256, 0, stream>>>(x, xT);

  for (int layer = 0; layer < 3; ++layer) {
    const float* A;   int K;
    const float* wih; const float* whh; const float* bih; const float* bhh;
    if (layer == 0) {
      A = xT; K = NMELS;
      wih = wih0; whh = whh0; bih = bih0; bhh = bhh0;
    } else {
      A = act; K = NH;
      wih = wih_rest + (size_t)(layer - 1) * NG * NH;
      whh = whh_rest + (size_t)(layer - 1) * NG * NH;
      bih = bih_rest + (size_t)(layer - 1) * NG;
      bhh = bhh_rest + (size_t)(layer - 1) * NG;
    }
    hipMemsetAsync(hsp_hi, 0, 2 * hsp_b, stream);  // h(-1) = 0 (both parities)
    for (int c0 = 0; c0 < T_FRAMES; c0 += Tc) {
      dim3 gg(NG / 64, Tc);
      k_gemm_xp<<<gg, 256, 0, stream>>>(A, wih, bih, xp, K, c0);
      hipMemsetAsync(bar, 0, NGRP * 64 * sizeof(unsigned), stream);
      k_gru_layer<<<NBLK, 512, 0, stream>>>(xp, whh, bhh, act,
                                            hsp_hi, hsp_lo, bar, c0, c0 + Tc);
    }
  }

  k_proj<<<BATCH, FCD, 0, stream>>>(act, wp, bp, out);
}

// Round 6
// 11936.906 us; speedup vs baseline: 2.5190x; 1.5914x over previous
//
#include <hip/hip_runtime.h>
#include <math.h>
#include <stdint.h>

#define T_FRAMES 256
#define BATCH    64
#define NH       1024
#define NG       3072   // 3*NH
#define NMELS    80
#define FCD      256

// ---- persistent GRU geometry ----
#define NGRP   4                  // batch groups
#define GB     16                 // batches per group (MFMA N)
#define JBLK   16                 // j's per block (MFMA M)
#define NBLK_G 64                 // blocks per group = NH/JBLK
#define NBLK   (NGRP * NBLK_G)    // 256 blocks = 1/CU
#define WAVES  8
#define KSL    (NH / WAVES)       // 128 k per wave
#define KTW    (KSL / 32)         // 4 ktiles per wave

typedef __bf16 bf16x8 __attribute__((ext_vector_type(8)));
typedef float  f32x4  __attribute__((ext_vector_type(4)));

// IC-coherent access: sc0 sc1 = bypass L1/L2, read/write at device coherence
// point (Infinity Cache). No wb/inv fences needed for cross-XCD exchange.
__device__ __forceinline__ uint4 ld_b128_coh(const uint32_t* p) {
  uint4 r;
  asm volatile("global_load_dwordx4 %0, %1, off sc0 sc1"
               : "=v"(r) : "v"(p) : "memory");
  return r;
}
__device__ __forceinline__ void st_b32_coh(uint32_t* p, uint32_t v) {
  asm volatile("global_store_dword %0, %1, off sc0 sc1"
               :: "v"(p), "v"(v) : "memory");
}

// ---------------------------------------------------------------------------
__global__ __launch_bounds__(256) void k_transpose_x(
    const float* __restrict__ x, float* __restrict__ xT) {
  int t = blockIdx.x;
  __shared__ float tile[BATCH][NMELS + 1];
  for (int idx = threadIdx.x; idx < BATCH * NMELS; idx += 256) {
    int b = idx / NMELS, i = idx % NMELS;
    tile[b][i] = x[((size_t)b * T_FRAMES + t) * NMELS + i];
  }
  __syncthreads();
  for (int idx = threadIdx.x; idx < BATCH * NMELS; idx += 256) {
    int i = idx / BATCH, b = idx % BATCH;
    xT[((size_t)t * NMELS + i) * BATCH + b] = tile[b][i];
  }
}

// ---------------------------------------------------------------------------
// xp[ty][g][b] = sum_k A[t0+ty][k][b] * W[g][k] + bias[g]
__global__ __launch_bounds__(256) void k_gemm_xp(
    const float* __restrict__ A, const float* __restrict__ W,
    const float* __restrict__ bias, float* __restrict__ xp, int K, int t0) {
  int ty = blockIdx.y;
  int t  = t0 + ty;
  int g0 = blockIdx.x * 64;
  __shared__ float As[16][64];
  __shared__ float Bs[16][64];

  int tid = threadIdx.x;
  int b0 = (tid & 15) * 4;
  int gq = tid >> 4;
  int ar = tid >> 4;
  int ac = (tid & 15) * 4;
  int bg = tid & 63;
  int bk = (tid >> 6) * 4;

  float acc[4][4] = {{0.f}};
  const float* At = A + (size_t)t * K * BATCH;

  for (int k0 = 0; k0 < K; k0 += 16) {
    *(float4*)&As[ar][ac] = *(const float4*)&At[(size_t)(k0 + ar) * BATCH + ac];
    float4 w = *(const float4*)&W[(size_t)(g0 + bg) * K + k0 + bk];
    Bs[bk + 0][bg] = w.x; Bs[bk + 1][bg] = w.y;
    Bs[bk + 2][bg] = w.z; Bs[bk + 3][bg] = w.w;
    __syncthreads();
#pragma unroll
    for (int kt = 0; kt < 16; ++kt) {
      const float4 a  = *(const float4*)&As[kt][b0];
      const float4 g4 = *(const float4*)&Bs[kt][gq * 4];
      const float av[4] = {a.x, a.y, a.z, a.w};
      const float gv[4] = {g4.x, g4.y, g4.z, g4.w};
#pragma unroll
      for (int gi = 0; gi < 4; ++gi)
#pragma unroll
        for (int bj = 0; bj < 4; ++bj)
          acc[gi][bj] = fmaf(gv[gi], av[bj], acc[gi][bj]);
    }
    __syncthreads();
  }
#pragma unroll
  for (int gi = 0; gi < 4; ++gi) {
    int g = g0 + gq * 4 + gi;
    float bv = bias[g];
    float4 o = make_float4(acc[gi][0] + bv, acc[gi][1] + bv,
                           acc[gi][2] + bv, acc[gi][3] + bv);
    *(float4*)&xp[((size_t)ty * NG + g) * BATCH + b0] = o;
  }
}

// ---------------------------------------------------------------------------
// Persistent MFMA GRU layer. 256 blocks x 512 threads, 1 block/CU.
// Group = 64 blocks (2 XCDs), owns GB=16 batches. Block owns JBLK=16 j's.
// Weights pinned in VGPRs (bf16 hi/lo). h exchanged via IC with sc0/sc1
// loads/stores packed as u32 = (hi<<16)|lo per (j,b); ping-pong on t parity.
// Barrier: relaxed agent-scope counter (no cache flushes).
__global__ __launch_bounds__(512, 2) void k_gru_layer(
    const float* __restrict__ xp,     // [Tc][NG][BATCH], frame t0 first
    const float* __restrict__ whh,    // [NG][NH]
    const float* __restrict__ bhh,    // [NG]
    float* __restrict__ act,          // [T][NH][BATCH]
    uint32_t* __restrict__ hsp,       // [2][NGRP][GB][NH] packed u32
    unsigned* __restrict__ bar,       // [NGRP][64]
    int t0, int tEnd) {
  const int tid = threadIdx.x;
  const int l   = tid & 63;
  const int wv  = tid >> 6;
  // XCD-friendly: group g <- XCDs {2g, 2g+1}
  const int grp    = (blockIdx.x & 7) >> 1;
  const int blk_in = (blockIdx.x >> 3) * 2 + (blockIdx.x & 1);
  const int j0 = blk_in * JBLK;
  const int n0 = grp * GB;

  __shared__ float part[3][JBLK][GB];   // 3 KB

  // ---- stage weights into VGPRs as bf16 hi/lo fragments ----
  const int row_j = j0 + (l & 15);
  const int kbase = wv * KSL + (l >> 4) * 8;
  bf16x8 whi[3][KTW], wlo[3][KTW];
#pragma unroll
  for (int g = 0; g < 3; ++g) {
#pragma unroll
    for (int kt = 0; kt < KTW; ++kt) {
      const float* wp8 = whh + (size_t)(g * NH + row_j) * NH + kbase + kt * 32;
      float4 w0 = *(const float4*)wp8;
      float4 w1 = *(const float4*)(wp8 + 4);
      float f[8] = {w0.x, w0.y, w0.z, w0.w, w1.x, w1.y, w1.z, w1.w};
      bf16x8 hi, lo;
#pragma unroll
      for (int e = 0; e < 8; ++e) {
        __bf16 hv = (__bf16)f[e];
        hi[e] = hv;
        lo[e] = (__bf16)(f[e] - (float)hv);
      }
      whi[g][kt] = hi; wlo[g][kt] = lo;
    }
  }
  // pin fragments in registers (defeat rematerialization into the t-loop)
#pragma unroll
  for (int g = 0; g < 3; ++g)
#pragma unroll
    for (int kt = 0; kt < KTW; ++kt)
      asm volatile("" : "+v"(whi[g][kt]), "+v"(wlo[g][kt]));

  // gating-thread state (tid < 256): jl = tid>>4, b = tid&15
  const int jl = tid >> 4;
  const int b  = tid & 15;
  const int j  = j0 + (jl & 15);
  float hprev = 0.f, bhr = 0.f, bhz = 0.f, bhn = 0.f;
  if (tid < 256) {
    if (t0 > 0) hprev = act[((size_t)(t0 - 1) * NH + j) * BATCH + n0 + b];
    bhr = bhh[j]; bhz = bhh[NH + j]; bhn = bhh[2 * NH + j];
  }

  for (int i = tid; i < 3 * JBLK * GB; i += 512) ((float*)part)[i] = 0.f;
  __syncthreads();

  const uint32_t SEL_HI = 0x07060302u;   // [E2 E3 O2 O3]
  const uint32_t SEL_LO = 0x05040100u;   // [E0 E1 O0 O1]

  unsigned gen = 1;
  for (int t = t0; t < tEnd; ++t) {
    const int rpar = (t + 1) & 1;   // where h(t-1) lives
    const int wpar = t & 1;         // where h(t) goes

    // early xp loads (overlap with MFMA phase)
    float xr = 0.f, xz = 0.f, xn = 0.f;
    if (tid < 256) {
      const float* xpt = xp + (size_t)(t - t0) * NG * BATCH;
      xr = xpt[(size_t)(0 * NH + j) * BATCH + n0 + b];
      xz = xpt[(size_t)(1 * NH + j) * BATCH + n0 + b];
      xn = xpt[(size_t)(2 * NH + j) * BATCH + n0 + b];
    }

    // ---- coherent fragment loads: h(t-1) for this wave's k-slice ----
    const uint32_t* hrow =
        hsp + ((size_t)(rpar * NGRP + grp) * GB + (l & 15)) * NH;
    uint4 q[KTW][2];
#pragma unroll
    for (int kt = 0; kt < KTW; ++kt) {
      const uint32_t* p = hrow + kbase + kt * 32 - (l >> 4) * 8 + (l >> 4) * 8;
      q[kt][0] = ld_b128_coh(p);
      q[kt][1] = ld_b128_coh(p + 4);
    }
    asm volatile("s_waitcnt vmcnt(0)" ::: "memory");
    __builtin_amdgcn_sched_barrier(0);

    // unpack to bf16x8 hi/lo fragments (2 v_perm per k-pair)
    bf16x8 bh[KTW], bl[KTW];
#pragma unroll
    for (int kt = 0; kt < KTW; ++kt) {
      union { uint32_t u[4]; bf16x8 v; } H, L;
      H.u[0] = __builtin_amdgcn_perm(q[kt][0].y, q[kt][0].x, SEL_HI);
      L.u[0] = __builtin_amdgcn_perm(q[kt][0].y, q[kt][0].x, SEL_LO);
      H.u[1] = __builtin_amdgcn_perm(q[kt][0].w, q[kt][0].z, SEL_HI);
      L.u[1] = __builtin_amdgcn_perm(q[kt][0].w, q[kt][0].z, SEL_LO);
      H.u[2] = __builtin_amdgcn_perm(q[kt][1].y, q[kt][1].x, SEL_HI);
      L.u[2] = __builtin_amdgcn_perm(q[kt][1].y, q[kt][1].x, SEL_LO);
      H.u[3] = __builtin_amdgcn_perm(q[kt][1].w, q[kt][1].z, SEL_HI);
      L.u[3] = __builtin_amdgcn_perm(q[kt][1].w, q[kt][1].z, SEL_LO);
      bh[kt] = H.v; bl[kt] = L.v;
    }

    // ---- MFMA: 3-pass bf16 hi/lo split ----
    f32x4 acc[3];
#pragma unroll
    for (int g = 0; g < 3; ++g) acc[g] = (f32x4){0.f, 0.f, 0.f, 0.f};
#pragma unroll
    for (int kt = 0; kt < KTW; ++kt) {
#pragma unroll
      for (int g = 0; g < 3; ++g) {
        acc[g] = __builtin_amdgcn_mfma_f32_16x16x32_bf16(whi[g][kt], bh[kt], acc[g], 0, 0, 0);
        acc[g] = __builtin_amdgcn_mfma_f32_16x16x32_bf16(whi[g][kt], bl[kt], acc[g], 0, 0, 0);
        acc[g] = __builtin_amdgcn_mfma_f32_16x16x32_bf16(wlo[g][kt], bh[kt], acc[g], 0, 0, 0);
      }
    }
    // cross-wave reduce: C row=(l>>4)*4+q, col=l&15
#pragma unroll
    for (int g = 0; g < 3; ++g)
#pragma unroll
      for (int qi = 0; qi < 4; ++qi)
        atomicAdd(&part[g][(l >> 4) * 4 + qi][l & 15], acc[g][qi]);
    __syncthreads();

    // ---- gating ----
    if (tid < 256) {
      const float ghr = part[0][jl][b];
      const float ghz = part[1][jl][b];
      const float ghn = part[2][jl][b];
      part[0][jl][b] = 0.f; part[1][jl][b] = 0.f; part[2][jl][b] = 0.f;

      const float r = 1.f / (1.f + expf(-(xr + ghr + bhr)));
      const float z = 1.f / (1.f + expf(-(xz + ghz + bhz)));
      const float n = tanhf(xn + r * (ghn + bhn));
      const float h = (1.f - z) * n + z * hprev;
      hprev = h;
      act[((size_t)t * NH + j) * BATCH + n0 + b] = h;

      union { __bf16 f; uint16_t u; } hh, hl;
      hh.f = (__bf16)h;
      hl.f = (__bf16)(h - (float)hh.f);
      st_b32_coh(hsp + ((size_t)(wpar * NGRP + grp) * GB + b) * NH + j,
                 ((uint32_t)hh.u << 16) | hl.u);
    }

    // ---- per-group barrier: counter only, no cache flushes ----
    if (t + 1 < tEnd) {
      __syncthreads();   // drains vmcnt -> h(t) committed at IC
      if (tid == 0) {
        unsigned* c = bar + grp * 64;
        __hip_atomic_fetch_add(c, 1u, __ATOMIC_RELAXED, __HIP_MEMORY_SCOPE_AGENT);
        const unsigned tgt = gen * NBLK_G;
        while (__hip_atomic_load(c, __ATOMIC_RELAXED, __HIP_MEMORY_SCOPE_AGENT) < tgt)
          __builtin_amdgcn_s_sleep(1);
      }
      ++gen;
      __syncthreads();
    }
  }
}

// ---------------------------------------------------------------------------
__global__ __launch_bounds__(256) void k_proj(
    const float* __restrict__ act, const float* __restrict__ wp,
    const float* __restrict__ bp, float* __restrict__ out) {
  int b = blockIdx.x;
  int f = threadIdx.x;
  __shared__ float hs[NH];
  __shared__ float red[FCD];

  const float* hlast = act + (size_t)(T_FRAMES - 1) * NH * BATCH + b;
  for (int k = f; k < NH; k += FCD) hs[k] = hlast[(size_t)k * BATCH];
  __syncthreads();

  float acc = bp[f];
  const float* wrow = wp + (size_t)f * NH;
#pragma unroll 4
  for (int k = 0; k < NH; k += 4) {
    const float4 w4 = *(const float4*)&wrow[k];
    acc = fmaf(w4.x, hs[k], acc);
    acc = fmaf(w4.y, hs[k + 1], acc);
    acc = fmaf(w4.z, hs[k + 2], acc);
    acc = fmaf(w4.w, hs[k + 3], acc);
  }
  red[f] = acc * acc;
  __syncthreads();
  for (int s = FCD / 2; s > 0; s >>= 1) {
    if (f < s) red[f] += red[f + s];
    __syncthreads();
  }
  float nrm = sqrtf(red[0]);
  out[(size_t)b * FCD + f] = acc / fmaxf(nrm, 1e-12f);
}

// ---------------------------------------------------------------------------
extern "C" void kernel_launch(void* const* d_in, const int* in_sizes, int n_in,
                              void* d_out, int out_size, void* d_ws, size_t ws_size,
                              hipStream_t stream) {
  const float* x        = (const float*)d_in[0];
  const float* wih0     = (const float*)d_in[1];
  const float* whh0     = (const float*)d_in[2];
  const float* bih0     = (const float*)d_in[3];
  const float* bhh0     = (const float*)d_in[4];
  const float* wih_rest = (const float*)d_in[5];
  const float* whh_rest = (const float*)d_in[6];
  const float* bih_rest = (const float*)d_in[7];
  const float* bhh_rest = (const float*)d_in[8];
  const float* wp       = (const float*)d_in[9];
  const float* bp       = (const float*)d_in[10];
  float* out = (float*)d_out;

  // ---- workspace layout (bytes) ----
  const size_t act_b = (size_t)T_FRAMES * NH * BATCH * 4;     // 67,108,864
  const size_t xT_b  = (size_t)T_FRAMES * NMELS * BATCH * 4;  //  5,242,880
  const size_t hsp_b = (size_t)2 * NGRP * GB * NH * 4;        //    524,288
  const size_t bar_b = 4096;
  const size_t fixed = act_b + xT_b + hsp_b + bar_b;

  char* wsb = (char*)d_ws;
  float*     act = (float*)wsb;
  float*     xT  = (float*)(wsb + act_b);
  uint32_t*  hsp = (uint32_t*)(wsb + act_b + xT_b);
  unsigned*  bar = (unsigned*)(wsb + act_b + xT_b + hsp_b);
  float*     xp  = (float*)(wsb + fixed);

  int Tc = 0;
  for (int c = T_FRAMES; c >= 1; c >>= 1) {
    if (fixed + (size_t)c * NG * BATCH * 4 <= ws_size) { Tc = c; break; }
  }
  if (Tc == 0) return;

  k_transpose_x<<<T_FRAMES, 256, 0, stream>>>(x, xT);

  for (int layer = 0; layer < 3; ++layer) {
    const float* A;   int K;
    const float* wih; const float* whh; const float* bih; const float* bhh;
    if (layer == 0) {
      A = xT; K = NMELS;
      wih = wih0; whh = whh0; bih = bih0; bhh = bhh0;
    } else {
      A = act; K = NH;
      wih = wih_rest + (size_t)(layer - 1) * NG * NH;
      whh = whh_rest + (size_t)(layer - 1) * NG * NH;
      bih = bih_rest + (size_t)(layer - 1) * NG;
      bhh = bhh_rest + (size_t)(layer - 1) * NG;
    }
    hipMemsetAsync(hsp, 0, hsp_b, stream);   // h(-1) = 0 (both parities)
    for (int c0 = 0; c0 < T_FRAMES; c0 += Tc) {
      dim3 gg(NG / 64, Tc);
      k_gemm_xp<<<gg, 256, 0, stream>>>(A, wih, bih, xp, K, c0);
      hipMemsetAsync(bar, 0, NGRP * 64 * sizeof(unsigned), stream);
      k_gru_layer<<<NBLK, 512, 0, stream>>>(xp, whh, bhh, act,
                                            hsp, bar, c0, c0 + Tc);
    }
  }

  k_proj<<<BATCH, FCD, 0, stream>>>(act, wp, bp, out);
}

// Round 7
// 6401.196 us; speedup vs baseline: 4.6974x; 1.8648x over previous
//
#include <hip/hip_runtime.h>
#include <math.h>
#include <stdint.h>

#define T_FRAMES 256
#define BATCH    64
#define NH       1024
#define NG       3072   // 3*NH
#define NMELS    80
#define FCD      256

// ---- persistent GRU geometry ----
#define NGRP   4                  // batch groups
#define GB     16                 // batches per group (MFMA N)
#define JBLK   16                 // j's per block (MFMA M)
#define NBLK_G 64                 // blocks per group = NH/JBLK
#define NBLK   (NGRP * NBLK_G)    // 256 blocks = 1/CU
#define WAVES  8
#define KSL    (NH / WAVES)       // 128 k per wave
#define KTW    (KSL / 32)         // 4 ktiles per wave

typedef __bf16 bf16x8 __attribute__((ext_vector_type(8)));
typedef float  f32x4  __attribute__((ext_vector_type(4)));

// IC-coherent access (sc0 sc1): bypass L1/L2, serialize at Infinity Cache.
__device__ __forceinline__ uint4 ld_b128_coh(const uint32_t* p) {
  uint4 r;
  asm volatile("global_load_dwordx4 %0, %1, off sc0 sc1"
               : "=v"(r) : "v"(p) : "memory");
  return r;
}
__device__ __forceinline__ uint32_t ld_b32_coh(const uint32_t* p) {
  uint32_t r;
  asm volatile("global_load_dword %0, %1, off sc0 sc1\n\ts_waitcnt vmcnt(0)"
               : "=v"(r) : "v"(p) : "memory");
  return r;
}
__device__ __forceinline__ void st_b32_coh(uint32_t* p, uint32_t v) {
  asm volatile("global_store_dword %0, %1, off sc0 sc1"
               :: "v"(p), "v"(v) : "memory");
}

// ---------------------------------------------------------------------------
__global__ __launch_bounds__(256) void k_transpose_x(
    const float* __restrict__ x, float* __restrict__ xT) {
  int t = blockIdx.x;
  __shared__ float tile[BATCH][NMELS + 1];
  for (int idx = threadIdx.x; idx < BATCH * NMELS; idx += 256) {
    int b = idx / NMELS, i = idx % NMELS;
    tile[b][i] = x[((size_t)b * T_FRAMES + t) * NMELS + i];
  }
  __syncthreads();
  for (int idx = threadIdx.x; idx < BATCH * NMELS; idx += 256) {
    int i = idx / BATCH, b = idx % BATCH;
    xT[((size_t)t * NMELS + i) * BATCH + b] = tile[b][i];
  }
}

// ---------------------------------------------------------------------------
// xp[ty][g][b] = sum_k A[t0+ty][k][b] * W[g][k] + bias[g]
__global__ __launch_bounds__(256) void k_gemm_xp(
    const float* __restrict__ A, const float* __restrict__ W,
    const float* __restrict__ bias, float* __restrict__ xp, int K, int t0) {
  int ty = blockIdx.y;
  int t  = t0 + ty;
  int g0 = blockIdx.x * 64;
  __shared__ float As[16][64];
  __shared__ float Bs[16][64];

  int tid = threadIdx.x;
  int b0 = (tid & 15) * 4;
  int gq = tid >> 4;
  int ar = tid >> 4;
  int ac = (tid & 15) * 4;
  int bg = tid & 63;
  int bk = (tid >> 6) * 4;

  float acc[4][4] = {{0.f}};
  const float* At = A + (size_t)t * K * BATCH;

  for (int k0 = 0; k0 < K; k0 += 16) {
    *(float4*)&As[ar][ac] = *(const float4*)&At[(size_t)(k0 + ar) * BATCH + ac];
    float4 w = *(const float4*)&W[(size_t)(g0 + bg) * K + k0 + bk];
    Bs[bk + 0][bg] = w.x; Bs[bk + 1][bg] = w.y;
    Bs[bk + 2][bg] = w.z; Bs[bk + 3][bg] = w.w;
    __syncthreads();
#pragma unroll
    for (int kt = 0; kt < 16; ++kt) {
      const float4 a  = *(const float4*)&As[kt][b0];
      const float4 g4 = *(const float4*)&Bs[kt][gq * 4];
      const float av[4] = {a.x, a.y, a.z, a.w};
      const float gv[4] = {g4.x, g4.y, g4.z, g4.w};
#pragma unroll
      for (int gi = 0; gi < 4; ++gi)
#pragma unroll
        for (int bj = 0; bj < 4; ++bj)
          acc[gi][bj] = fmaf(gv[gi], av[bj], acc[gi][bj]);
    }
    __syncthreads();
  }
#pragma unroll
  for (int gi = 0; gi < 4; ++gi) {
    int g = g0 + gq * 4 + gi;
    float bv = bias[g];
    float4 o = make_float4(acc[gi][0] + bv, acc[gi][1] + bv,
                           acc[gi][2] + bv, acc[gi][3] + bv);
    *(float4*)&xp[((size_t)ty * NG + g) * BATCH + b0] = o;
  }
}

// ---------------------------------------------------------------------------
// Persistent MFMA GRU layer. 256 blocks x 512 threads, 1 block/CU.
// Group = 64 blocks, owns GB=16 batches. Block owns JBLK=16 j's.
// Weight-hi fragments in LDS (96 KB, staged once); weight-lo in VGPRs.
// h exchanged via IC (sc0/sc1) as packed u32 (hi<<16|lo), parity ping-pong.
// Sync: per-block completion flags (plain coherent stores), wave-0 poll.
__global__ __launch_bounds__(512, 1) void k_gru_layer(
    const float* __restrict__ xp,     // [Tc][NG][BATCH], frame t0 first
    const float* __restrict__ whh,    // [NG][NH]
    const float* __restrict__ bhh,    // [NG]
    float* __restrict__ act,          // [T][NH][BATCH]
    uint32_t* __restrict__ hsp,       // [2][NGRP][GB][NH] packed u32
    uint32_t* __restrict__ flg,       // [NGRP][64] step-completion flags
    int t0, int tEnd) {
  const int tid = threadIdx.x;
  const int l   = tid & 63;
  const int wv  = tid >> 6;
  // XCD-friendly: group g <- XCDs {2g, 2g+1}
  const int grp    = (blockIdx.x & 7) >> 1;
  const int blk_in = (blockIdx.x >> 3) * 2 + (blockIdx.x & 1);
  const int j0 = blk_in * JBLK;
  const int n0 = grp * GB;

  __shared__ uint32_t wHs[3 * WAVES * KTW * 64 * 4];   // 96 KB hi fragments
  __shared__ float part[WAVES][3][JBLK][GB];           // 24 KB partials

  // ---- stage weights: hi -> LDS fragment slots, lo -> VGPRs ----
  const int row_j = j0 + (l & 15);
  const int kbase = wv * KSL + (l >> 4) * 8;
  bf16x8 wlo[3][KTW];
#pragma unroll
  for (int g = 0; g < 3; ++g) {
#pragma unroll
    for (int kt = 0; kt < KTW; ++kt) {
      const float* wp8 = whh + (size_t)(g * NH + row_j) * NH + kbase + kt * 32;
      float4 w0 = *(const float4*)wp8;
      float4 w1 = *(const float4*)(wp8 + 4);
      float f[8] = {w0.x, w0.y, w0.z, w0.w, w1.x, w1.y, w1.z, w1.w};
      bf16x8 hi, lo;
#pragma unroll
      for (int e = 0; e < 8; ++e) {
        __bf16 hv = (__bf16)f[e];
        hi[e] = hv;
        lo[e] = (__bf16)(f[e] - (float)hv);
      }
      *(bf16x8*)&wHs[(((g * WAVES + wv) * KTW + kt) * 64 + l) * 4] = hi;
      wlo[g][kt] = lo;
    }
  }

  // gating-thread state (tid < 256): jl = tid>>4, b = tid&15
  const int jl = tid >> 4;
  const int b  = tid & 15;
  const int j  = j0 + (jl & 15);
  float hprev = 0.f, bhr = 0.f, bhz = 0.f, bhn = 0.f;
  if (tid < 256) {
    if (t0 > 0) hprev = act[((size_t)(t0 - 1) * NH + j) * BATCH + n0 + b];
    bhr = bhh[j]; bhz = bhh[NH + j]; bhn = bhh[2 * NH + j];
  }
  __syncthreads();

  const uint32_t SEL_HI = 0x07060302u;
  const uint32_t SEL_LO = 0x05040100u;

  for (int t = t0, i = 0; t < tEnd; ++t, ++i) {
    const int rpar = (t + 1) & 1;   // parity holding h(t-1)
    const int wpar = t & 1;         // parity receiving h(t)

    // early xp loads (plain, L2) — overlap with poll + h loads
    float xr = 0.f, xz = 0.f, xn = 0.f;
    if (tid < 256) {
      const float* xpt = xp + (size_t)(t - t0) * NG * BATCH;
      xr = xpt[(size_t)(0 * NH + j) * BATCH + n0 + b];
      xz = xpt[(size_t)(1 * NH + j) * BATCH + n0 + b];
      xn = xpt[(size_t)(2 * NH + j) * BATCH + n0 + b];
    }

    // ---- wait for all producers of h(t-1): poll 64 flags (wave 0) ----
    if (i > 0) {
      if (wv == 0) {
        const uint32_t tgt = (uint32_t)i;
        while (true) {
          uint32_t f = ld_b32_coh(flg + grp * NBLK_G + l);
          if (__all((int)(f >= tgt))) break;
          __builtin_amdgcn_s_sleep(2);
        }
      }
      __syncthreads();
    }

    // ---- coherent fragment loads: h(t-1), this wave's k-slice ----
    const uint32_t* hrow =
        hsp + ((size_t)(rpar * NGRP + grp) * GB + (l & 15)) * NH;
    uint4 q[KTW][2];
#pragma unroll
    for (int kt = 0; kt < KTW; ++kt) {
      const uint32_t* p = hrow + kbase + kt * 32;
      q[kt][0] = ld_b128_coh(p);
      q[kt][1] = ld_b128_coh(p + 4);
    }
    asm volatile("s_waitcnt vmcnt(0)" ::: "memory");
    __builtin_amdgcn_sched_barrier(0);

    // unpack to bf16x8 hi/lo fragments
    bf16x8 bh[KTW], bl[KTW];
#pragma unroll
    for (int kt = 0; kt < KTW; ++kt) {
      union { uint32_t u[4]; bf16x8 v; } H, L;
      H.u[0] = __builtin_amdgcn_perm(q[kt][0].y, q[kt][0].x, SEL_HI);
      L.u[0] = __builtin_amdgcn_perm(q[kt][0].y, q[kt][0].x, SEL_LO);
      H.u[1] = __builtin_amdgcn_perm(q[kt][0].w, q[kt][0].z, SEL_HI);
      L.u[1] = __builtin_amdgcn_perm(q[kt][0].w, q[kt][0].z, SEL_LO);
      H.u[2] = __builtin_amdgcn_perm(q[kt][1].y, q[kt][1].x, SEL_HI);
      L.u[2] = __builtin_amdgcn_perm(q[kt][1].y, q[kt][1].x, SEL_LO);
      H.u[3] = __builtin_amdgcn_perm(q[kt][1].w, q[kt][1].z, SEL_HI);
      L.u[3] = __builtin_amdgcn_perm(q[kt][1].w, q[kt][1].z, SEL_LO);
      bh[kt] = H.v; bl[kt] = L.v;
    }

    // ---- MFMA: 3-pass bf16 hi/lo split; w-hi streamed from LDS ----
    f32x4 acc[3];
#pragma unroll
    for (int g = 0; g < 3; ++g) acc[g] = (f32x4){0.f, 0.f, 0.f, 0.f};
#pragma unroll
    for (int kt = 0; kt < KTW; ++kt) {
#pragma unroll
      for (int g = 0; g < 3; ++g) {
        const bf16x8 whi =
            *(const bf16x8*)&wHs[(((g * WAVES + wv) * KTW + kt) * 64 + l) * 4];
        acc[g] = __builtin_amdgcn_mfma_f32_16x16x32_bf16(whi, bh[kt], acc[g], 0, 0, 0);
        acc[g] = __builtin_amdgcn_mfma_f32_16x16x32_bf16(whi, bl[kt], acc[g], 0, 0, 0);
        acc[g] = __builtin_amdgcn_mfma_f32_16x16x32_bf16(wlo[g][kt], bh[kt], acc[g], 0, 0, 0);
      }
    }

    // ---- per-wave partials -> LDS (plain stores; summed by gating threads)
#pragma unroll
    for (int g = 0; g < 3; ++g)
#pragma unroll
      for (int qi = 0; qi < 4; ++qi)
        part[wv][g][(l >> 4) * 4 + qi][l & 15] = acc[g][qi];
    __syncthreads();

    // ---- gating ----
    if (tid < 256) {
      float ghr = 0.f, ghz = 0.f, ghn = 0.f;
#pragma unroll
      for (int ww = 0; ww < WAVES; ++ww) {
        ghr += part[ww][0][jl][b];
        ghz += part[ww][1][jl][b];
        ghn += part[ww][2][jl][b];
      }
      const float r = 1.f / (1.f + expf(-(xr + ghr + bhr)));
      const float z = 1.f / (1.f + expf(-(xz + ghz + bhz)));
      const float n = tanhf(xn + r * (ghn + bhn));
      const float h = (1.f - z) * n + z * hprev;
      hprev = h;
      act[((size_t)t * NH + j) * BATCH + n0 + b] = h;

      union { __bf16 f; uint16_t u; } hh, hl;
      hh.f = (__bf16)h;
      hl.f = (__bf16)(h - (float)hh.f);
      st_b32_coh(hsp + ((size_t)(wpar * NGRP + grp) * GB + b) * NH + j,
                 ((uint32_t)hh.u << 16) | hl.u);
    }

    // ---- publish completion: barrier drains all stores, then flag ----
    __syncthreads();   // compiler emits s_waitcnt vmcnt(0) before s_barrier
    if (tid == 0) st_b32_coh(flg + grp * NBLK_G + blk_in, (uint32_t)(i + 1));
  }
}

// ---------------------------------------------------------------------------
__global__ __launch_bounds__(256) void k_proj(
    const float* __restrict__ act, const float* __restrict__ wp,
    const float* __restrict__ bp, float* __restrict__ out) {
  int b = blockIdx.x;
  int f = threadIdx.x;
  __shared__ float hs[NH];
  __shared__ float red[FCD];

  const float* hlast = act + (size_t)(T_FRAMES - 1) * NH * BATCH + b;
  for (int k = f; k < NH; k += FCD) hs[k] = hlast[(size_t)k * BATCH];
  __syncthreads();

  float acc = bp[f];
  const float* wrow = wp + (size_t)f * NH;
#pragma unroll 4
  for (int k = 0; k < NH; k += 4) {
    const float4 w4 = *(const float4*)&wrow[k];
    acc = fmaf(w4.x, hs[k], acc);
    acc = fmaf(w4.y, hs[k + 1], acc);
    acc = fmaf(w4.z, hs[k + 2], acc);
    acc = fmaf(w4.w, hs[k + 3], acc);
  }
  red[f] = acc * acc;
  __syncthreads();
  for (int s = FCD / 2; s > 0; s >>= 1) {
    if (f < s) red[f] += red[f + s];
    __syncthreads();
  }
  float nrm = sqrtf(red[0]);
  out[(size_t)b * FCD + f] = acc / fmaxf(nrm, 1e-12f);
}

// ---------------------------------------------------------------------------
extern "C" void kernel_launch(void* const* d_in, const int* in_sizes, int n_in,
                              void* d_out, int out_size, void* d_ws, size_t ws_size,
                              hipStream_t stream) {
  const float* x        = (const float*)d_in[0];
  const float* wih0     = (const float*)d_in[1];
  const float* whh0     = (const float*)d_in[2];
  const float* bih0     = (const float*)d_in[3];
  const float* bhh0     = (const float*)d_in[4];
  const float* wih_rest = (const float*)d_in[5];
  const float* whh_rest = (const float*)d_in[6];
  const float* bih_rest = (const float*)d_in[7];
  const float* bhh_rest = (const float*)d_in[8];
  const float* wp       = (const float*)d_in[9];
  const float* bp       = (const float*)d_in[10];
  float* out = (float*)d_out;

  // ---- workspace layout (bytes) ----
  const size_t act_b = (size_t)T_FRAMES * NH * BATCH * 4;     // 67,108,864
  const size_t xT_b  = (size_t)T_FRAMES * NMELS * BATCH * 4;  //  5,242,880
  const size_t hsp_b = (size_t)2 * NGRP * GB * NH * 4;        //    524,288
  const size_t flg_b = 4096;
  const size_t fixed = act_b + xT_b + hsp_b + flg_b;

  char* wsb = (char*)d_ws;
  float*     act = (float*)wsb;
  float*     xT  = (float*)(wsb + act_b);
  uint32_t*  hsp = (uint32_t*)(wsb + act_b + xT_b);
  uint32_t*  flg = (uint32_t*)(wsb + act_b + xT_b + hsp_b);
  float*     xp  = (float*)(wsb + fixed);

  int Tc = 0;
  for (int c = T_FRAMES; c >= 1; c >>= 1) {
    if (fixed + (size_t)c * NG * BATCH * 4 <= ws_size) { Tc = c; break; }
  }
  if (Tc == 0) return;

  k_transpose_x<<<T_FRAMES, 256, 0, stream>>>(x, xT);

  for (int layer = 0; layer < 3; ++layer) {
    const float* A;   int K;
    const float* wih; const float* whh; const float* bih; const float* bhh;
    if (layer == 0) {
      A = xT; K = NMELS;
      wih = wih0; whh = whh0; bih = bih0; bhh = bhh0;
    } else {
      A = act; K = NH;
      wih = wih_rest + (size_t)(layer - 1) * NG * NH;
      whh = whh_rest + (size_t)(layer - 1) * NG * NH;
      bih = bih_rest + (size_t)(layer - 1) * NG;
      bhh = bhh_rest + (size_t)(layer - 1) * NG;
    }
    hipMemsetAsync(hsp, 0, hsp_b, stream);   // h(-1) = 0 (both parities)
    for (int c0 = 0; c0 < T_FRAMES; c0 += Tc) {
      dim3 gg(NG / 64, Tc);
      k_gemm_xp<<<gg, 256, 0, stream>>>(A, wih, bih, xp, K, c0);
      hipMemsetAsync(flg, 0, NGRP * NBLK_G * sizeof(uint32_t), stream);
      k_gru_layer<<<NBLK, 512, 0, stream>>>(xp, whh, bhh, act,
                                            hsp, flg, c0, c0 + Tc);
    }
  }

  k_proj<<<BATCH, FCD, 0, stream>>>(act, wp, bp, out);
}